// Round 9
// baseline (979.485 us; speedup 1.0000x reference)
//
#include <hip/hip_runtime.h>
#include <stdint.h>

#define N_SEQ 16384
#define T_LEN 16
#define E_DIM 256
#define H_DIM 256
#define K_DIM 512
#define B_SAMP 128
#define V_SIZE 10000

typedef __bf16 bf16x8 __attribute__((ext_vector_type(8)));
typedef float  f32x4  __attribute__((ext_vector_type(4)));
typedef unsigned short ush;

__device__ __forceinline__ ush f2bf(float x) {
  unsigned int u = __float_as_uint(x);
  u = (u + 0x7fffu + ((u >> 16) & 1u)) >> 16;
  return (ush)u;
}
__device__ __forceinline__ float bf2f(ush v) {
  return __uint_as_float(((unsigned int)v) << 16);
}
__device__ __forceinline__ float sigmoidf_(float x) {
  return 1.0f / (1.0f + __expf(-x));
}
__device__ __forceinline__ float tanhf_(float x) {
  float e = __expf(2.0f * x);
  return 1.0f - 2.0f / (e + 1.0f);
}
__device__ __forceinline__ void glds16(const void* g, const void* l) {
  __builtin_amdgcn_global_load_lds(
      (const __attribute__((address_space(1))) unsigned int*)g,
      (__attribute__((address_space(3))) unsigned int*)l, 16, 0, 0);
}

// ---------------- prep kernels ----------------

__global__ __launch_bounds__(256) void k_lens(const int* __restrict__ tok, int* __restrict__ lens,
                                              int* __restrict__ hist) {
  __shared__ int lh[17];
  if (threadIdx.x < 17) lh[threadIdx.x] = 0;
  __syncthreads();
  int n = blockIdx.x * 256 + threadIdx.x;
  const int* r = tok + n * T_LEN;
  int c = 0;
#pragma unroll
  for (int t = 0; t < T_LEN; ++t) c += (r[t] != 0);
  lens[n] = c;
  atomicAdd(&lh[c], 1);
  __syncthreads();
  if (threadIdx.x < 17 && lh[threadIdx.x]) atomicAdd(&hist[threadIdx.x], lh[threadIdx.x]);
}

// descending-length bucket starts; cnts_f[t]=count(len>=t) (incl. fwd graduating copy step),
// cnts_b[t]=count(len>t) (bwd rows activate late; pre-activation h==0 in both buffers)
__global__ void k_offsets(const int* __restrict__ hist, int* __restrict__ cursor,
                          int* __restrict__ cnts_f, int* __restrict__ cnts_b) {
  if (threadIdx.x == 0) {
    int off = 0;
    for (int l = 16; l >= 0; --l) { cursor[l] = off; off += hist[l]; }
    for (int t = 0; t < 16; ++t) {
      int cf = 0, cb = 0;
      for (int l = t; l <= 16; ++l) cf += hist[l];
      for (int l = t + 1; l <= 16; ++l) cb += hist[l];
      cnts_f[t] = cf;
      cnts_b[t] = cb;
    }
  }
}

__global__ __launch_bounds__(256) void k_scatter(const int* __restrict__ lens, int* __restrict__ cursor,
                                                 int* __restrict__ perm, int* __restrict__ pinv,
                                                 int* __restrict__ plens) {
  int n = blockIdx.x * 256 + threadIdx.x;
  int l = lens[n];
  int pos = atomicAdd(&cursor[l], 1);
  perm[pos] = n;
  pinv[n] = pos;
  plens[pos] = l;
}

// gather form: coalesced writes, tok (1 MB) is L2-resident
__global__ __launch_bounds__(256) void k_tokperm(const int* __restrict__ tok, const int* __restrict__ perm,
                                                 int* __restrict__ tokperm) {
  int id = blockIdx.x * 256 + threadIdx.x;  // < T_LEN * N_SEQ
  int t = id >> 14;                          // N_SEQ = 2^14
  int pos = id & (N_SEQ - 1);
  tokperm[id] = tok[perm[pos] * T_LEN + t];
}

__global__ __launch_bounds__(256) void k_embcvt(const float* __restrict__ emb, ush* __restrict__ out) {
  int i = blockIdx.x * 256 + threadIdx.x;
  out[i] = f2bf(emb[i]);
}

// Permuted weights: wpt[p][k], p = nb*128 + wcl*64 + q*16 + jj  <->
// j = nb*32 + wcl*16 + jj, gate-row r = q*256 + j; k<256 -> W_ih[r][k], else W_hh[r][k-256].
__global__ __launch_bounds__(256) void k_wprep(const float* __restrict__ Wih_f, const float* __restrict__ Whh_f,
                                               const float* __restrict__ Wih_b, const float* __restrict__ Whh_b,
                                               ush* __restrict__ wpt_f, ush* __restrict__ wpt_b) {
  int id = blockIdx.x * 256 + threadIdx.x;  // < 2*1024*512
  int dir = id >> 19;
  int rem = id & ((1 << 19) - 1);
  int p = rem >> 9;
  int k = rem & 511;
  int nb = p >> 7, wcl = (p >> 6) & 1, q = (p >> 4) & 3, jj = p & 15;
  int r = q * 256 + nb * 32 + wcl * 16 + jj;
  const float* Wih = dir ? Wih_b : Wih_f;
  const float* Whh = dir ? Whh_b : Whh_f;
  float v = (k < 256) ? Wih[r * 256 + k] : Whh[r * 256 + (k - 256)];
  ush* o = dir ? wpt_b : wpt_f;
  o[p * 512 + k] = f2bf(v);
}

// ---------------- LSTM step: counted-vmcnt 2-deep pipelined GEMM + fused cell ----------------
// Tile 128 rows x 128 pcols (=32 hidden j x 4 gates), 256 thr / 4 waves (2x2, wave tile 64x64).
// K=512 in 8 chunks of 64; 2 chunk-buffers (A16K+B16K each, 64KB total). Per chunk:
//   s_waitcnt vmcnt(8)  (current chunk's 8 loads done; NEXT chunk's 8 stay in flight)
//   s_barrier; sched_barrier; 32 MFMA; s_barrier; stage(kt+2) into the buffer just freed.
// No vmcnt(0) drain in the loop (T3/T4). XOR-swizzled 128B rows (measured conflict-free).
// XCD decode: b&1=dir, nblk=((b>>1)&3)*2+((b>>3)&1), rt=b>>4 -> each XCD owns 1 dir x 2 B-slices.

__global__ __launch_bounds__(256, 2)
void k_step(const ush* __restrict__ embbf, const int* __restrict__ tokperm,
            const int* __restrict__ plens,
            const int* __restrict__ cnts_f, const int* __restrict__ cnts_b,
            const ush* __restrict__ wpt_f, const ush* __restrict__ wpt_b,
            const float* __restrict__ bias_f, const float* __restrict__ bias_b,
            const ush* __restrict__ hr_f, ush* __restrict__ hw_f,
            const ush* __restrict__ hr_b, ush* __restrict__ hw_b,
            float* __restrict__ cT_f, float* __restrict__ cT_b,
            int s) {
  const int b = blockIdx.x;
  const int dir = b & 1;
  const int nblk = ((b >> 1) & 3) * 2 + ((b >> 3) & 1);
  const int rt = b >> 4;
  const int t = dir ? (15 - s) : s;
  const int cnt = dir ? cnts_b[t] : cnts_f[t];
  const int m0 = rt * 128;
  if (m0 >= cnt) return;

  const ush* wpt = dir ? wpt_b : wpt_f;
  const float* bias = dir ? bias_b : bias_f;
  const ush* hr = dir ? hr_b : hr_f;
  ush* hw = dir ? hw_b : hw_f;
  float* cT = dir ? cT_b : cT_f;

  __shared__ __align__(128) unsigned char lds[2][32768];  // [buf]: A [0,16K), B [16K,32K)

  const int tid = threadIdx.x;
  const int lane = tid & 63;
  const int w = tid >> 6;        // 4 waves
  const int wr = w >> 1, wc = w & 1;
  const int l8 = lane >> 3, l7 = lane & 7;
  const int frow = lane & 15, fkq = lane >> 4;

  // ---- staging offsets: 4 A-ops + 4 B-ops per wave per chunk, 8 rows each ----
  unsigned aoffE[4], aoffH[4], boff[4];
#pragma unroll
  for (int i = 0; i < 4; ++i) {
    const int arow = 32 * w + 8 * i + l8;
    const int ach = l7 ^ (arow & 7);
    aoffE[i] = (unsigned)tokperm[t * N_SEQ + m0 + arow] * (E_DIM * 2) + ach * 16;
    aoffH[i] = (unsigned)(m0 + arow) * (H_DIM * 2) + ach * 16;
    boff[i]  = (unsigned)(nblk * 128 + arow) * (K_DIM * 2) + ach * 16;
  }
  const char* embc = (const char*)embbf;
  const char* hrc  = (const char*)hr;
  const char* wptc = (const char*)wpt;

  f32x4 acc[4][4] = {};

  auto stage = [&](int kt, int buf) {
    if (kt < 4) {
      const int ak = kt * 128;
#pragma unroll
      for (int i = 0; i < 4; ++i)
        glds16(embc + aoffE[i] + ak, &lds[buf][(32 * w + 8 * i) * 128]);
    } else {
      const int ak = (kt - 4) * 128;
#pragma unroll
      for (int i = 0; i < 4; ++i)
        glds16(hrc + aoffH[i] + ak, &lds[buf][(32 * w + 8 * i) * 128]);
    }
#pragma unroll
    for (int i = 0; i < 4; ++i)
      glds16(wptc + boff[i] + kt * 128, &lds[buf][16384 + (32 * w + 8 * i) * 128]);
  };
  auto compute = [&](int buf) {
#pragma unroll
    for (int ksub = 0; ksub < 2; ++ksub) {
      const int slot = ksub * 4 + fkq;
      bf16x8 av[4], bv[4];
#pragma unroll
      for (int fr = 0; fr < 4; ++fr) {
        const int row = wr * 64 + fr * 16 + frow;
        av[fr] = *(const bf16x8*)&lds[buf][row * 128 + ((slot ^ (row & 7)) * 16)];
      }
#pragma unroll
      for (int fc = 0; fc < 4; ++fc) {
        const int prow = wc * 64 + fc * 16 + frow;
        bv[fc] = *(const bf16x8*)&lds[buf][16384 + prow * 128 + ((slot ^ (prow & 7)) * 16)];
      }
      __builtin_amdgcn_s_setprio(1);
#pragma unroll
      for (int fr = 0; fr < 4; ++fr)
#pragma unroll
        for (int fc = 0; fc < 4; ++fc)
          acc[fr][fc] = __builtin_amdgcn_mfma_f32_16x16x32_bf16(av[fr], bv[fc], acc[fr][fc], 0, 0, 0);
      __builtin_amdgcn_s_setprio(0);
    }
  };

  stage(0, 0);
  stage(1, 1);
#pragma unroll
  for (int kt = 0; kt < 8; ++kt) {
    if (kt <= 6) asm volatile("s_waitcnt vmcnt(8)" ::: "memory");
    else         asm volatile("s_waitcnt vmcnt(0)" ::: "memory");
    __builtin_amdgcn_s_barrier();
    __builtin_amdgcn_sched_barrier(0);
    compute(kt & 1);
    if (kt <= 5) {
      __builtin_amdgcn_s_barrier();       // all waves done reading buf[kt&1]
      __builtin_amdgcn_sched_barrier(0);
      stage(kt + 2, kt & 1);              // refill freed buffer; stays in flight
    }
  }

  // ---- fused LSTM cell update: acc[fr][q] = gate q for hidden unit j ----
  const int j = nblk * 32 + wc * 16 + frow;
  const float b0 = bias[j], b1 = bias[256 + j], b2 = bias[512 + j], b3 = bias[768 + j];
#pragma unroll
  for (int fr = 0; fr < 4; ++fr) {
    const int n0 = m0 + wr * 64 + fr * 16 + fkq * 4;
    const int4 l4 = *(const int4*)&plens[n0];
    f32x4 cv = *(const f32x4*)&cT[(size_t)j * N_SEQ + n0];
    const f32x4 gi = acc[fr][0], gf = acc[fr][1], gg = acc[fr][2], go = acc[fr][3];
#pragma unroll
    for (int r = 0; r < 4; ++r) {
      const int lnv = (r == 0) ? l4.x : (r == 1) ? l4.y : (r == 2) ? l4.z : l4.w;
      const size_t hidx = (size_t)(n0 + r) * H_DIM + j;
      if (t < lnv) {
        const float iv = sigmoidf_(gi[r] + b0);
        const float fv = sigmoidf_(gf[r] + b1);
        const float gv = tanhf_(gg[r] + b2);
        const float ov = sigmoidf_(go[r] + b3);
        const bool first = dir ? (t == lnv - 1) : (t == 0);
        const float cn = fv * (first ? 0.0f : cv[r]) + iv * gv;
        cv[r] = cn;
        hw[hidx] = f2bf(ov * tanhf_(cn));
      } else if (!dir) {
        hw[hidx] = hr[hidx];  // fwd graduation copy; idempotent afterwards
      }
    }
    *(f32x4*)&cT[(size_t)j * N_SEQ + n0] = cv;
  }
}

// ---------------- segment-mean pool (before the linear layer) ----------------

__global__ __launch_bounds__(256) void k_pool(const ush* __restrict__ hf,
                                              const ush* __restrict__ hb,
                                              const int* __restrict__ pinv,
                                              const int* __restrict__ plen,
                                              float* __restrict__ pooled) {
  const int b = blockIdx.x, tid = threadIdx.x;
  int start = 0;
  for (int i = 0; i < b; ++i) start += plen[i];
  const int cnt = plen[b];
  float s0 = 0.f, s1 = 0.f;
  for (int r = 0; r < cnt; ++r) {
    const size_t pr = (size_t)pinv[start + r];
    s0 += bf2f(hf[pr * H_DIM + tid]);
    s1 += bf2f(hb[pr * H_DIM + tid]);
  }
  float inv = 1.0f / (float)cnt;
  pooled[b * 512 + tid] = s0 * inv;
  pooled[b * 512 + H_DIM + tid] = s1 * inv;
}

// ---------------- tiny linear (128x512x512) + L2 normalize, f32 ----------------

__global__ __launch_bounds__(256) void k_final(const float* __restrict__ pooled,
                                               const float* __restrict__ W,
                                               const float* __restrict__ bl,
                                               float* __restrict__ out) {
  const int b = blockIdx.x, tid = threadIdx.x;
  __shared__ float pv[512];
  __shared__ float pre[512];
  __shared__ float red[4];
  pv[tid] = pooled[b * 512 + tid];
  pv[tid + 256] = pooled[b * 512 + 256 + tid];
  __syncthreads();
#pragma unroll
  for (int half = 0; half < 2; ++half) {
    const int dd = tid + half * 256;
    const f32x4* wr = (const f32x4*)(W + (size_t)dd * 512);
    const f32x4* pvv = (const f32x4*)pv;
    float s = bl[dd];
#pragma unroll 4
    for (int k4 = 0; k4 < 128; ++k4) {
      f32x4 wv = wr[k4], xv = pvv[k4];
      s += wv[0] * xv[0] + wv[1] * xv[1] + wv[2] * xv[2] + wv[3] * xv[3];
    }
    pre[dd] = s;
  }
  __syncthreads();
  float ss = pre[tid] * pre[tid] + pre[tid + 256] * pre[tid + 256];
#pragma unroll
  for (int off = 32; off > 0; off >>= 1) ss += __shfl_down(ss, off, 64);
  if ((tid & 63) == 0) red[tid >> 6] = ss;
  __syncthreads();
  float tot = red[0] + red[1] + red[2] + red[3];
  float scale = 1.0f / fmaxf(sqrtf(tot), 1e-5f);
  out[b * 512 + tid] = pre[tid] * scale;
  out[b * 512 + 256 + tid] = pre[tid + 256] * scale;
}

// ---------------- launch ----------------

extern "C" void kernel_launch(void* const* d_in, const int* in_sizes, int n_in,
                              void* d_out, int out_size, void* d_ws, size_t ws_size,
                              hipStream_t stream) {
  const int* tok    = (const int*)d_in[0];
  const int* plen   = (const int*)d_in[1];
  const float* emb  = (const float*)d_in[2];
  const float* Wih_f = (const float*)d_in[3];
  const float* Whh_f = (const float*)d_in[4];
  const float* b_f   = (const float*)d_in[5];
  const float* Wih_b = (const float*)d_in[6];
  const float* Whh_b = (const float*)d_in[7];
  const float* b_b   = (const float*)d_in[8];
  const float* Wlin  = (const float*)d_in[9];
  const float* blin  = (const float*)d_in[10];
  float* out = (float*)d_out;

  char* ws = (char*)d_ws;
  size_t off = 0;
  auto alloc = [&](size_t bytes) {
    void* p = ws + off;
    off = (off + bytes + 255) & ~(size_t)255;
    return p;
  };
  ush* embbf   = (ush*)alloc((size_t)V_SIZE * E_DIM * 2);
  ush* wptf    = (ush*)alloc((size_t)1024 * K_DIM * 2);
  ush* wptb    = (ush*)alloc((size_t)1024 * K_DIM * 2);
  int* lens    = (int*)alloc((size_t)N_SEQ * 4);
  int* perm    = (int*)alloc((size_t)N_SEQ * 4);
  int* pinv    = (int*)alloc((size_t)N_SEQ * 4);
  int* plens   = (int*)alloc((size_t)N_SEQ * 4);
  int* tokperm = (int*)alloc((size_t)T_LEN * N_SEQ * 4);
  int* hist    = (int*)alloc(17 * 4);
  int* cursor  = (int*)alloc(17 * 4);
  int* cntsf   = (int*)alloc(16 * 4);
  int* cntsb   = (int*)alloc(16 * 4);
  ush* h0f     = (ush*)alloc((size_t)N_SEQ * H_DIM * 2);
  ush* h1f     = (ush*)alloc((size_t)N_SEQ * H_DIM * 2);
  ush* h0b     = (ush*)alloc((size_t)N_SEQ * H_DIM * 2);
  ush* h1b     = (ush*)alloc((size_t)N_SEQ * H_DIM * 2);
  float* cTf   = (float*)alloc((size_t)H_DIM * N_SEQ * 4);
  float* cTb   = (float*)alloc((size_t)H_DIM * N_SEQ * 4);
  float* pooled = (float*)alloc((size_t)B_SAMP * 512 * 4);

  hipMemsetAsync(hist, 0, 17 * 4, stream);
  hipMemsetAsync(h0f, 0, (size_t)N_SEQ * H_DIM * 2, stream);
  hipMemsetAsync(h1f, 0, (size_t)N_SEQ * H_DIM * 2, stream);
  hipMemsetAsync(h0b, 0, (size_t)N_SEQ * H_DIM * 2, stream);
  hipMemsetAsync(h1b, 0, (size_t)N_SEQ * H_DIM * 2, stream);

  k_lens<<<N_SEQ / 256, 256, 0, stream>>>(tok, lens, hist);
  k_offsets<<<1, 64, 0, stream>>>(hist, cursor, cntsf, cntsb);
  k_scatter<<<N_SEQ / 256, 256, 0, stream>>>(lens, cursor, perm, pinv, plens);
  k_tokperm<<<(T_LEN * N_SEQ) / 256, 256, 0, stream>>>(tok, perm, tokperm);
  k_embcvt<<<(V_SIZE * E_DIM) / 256, 256, 0, stream>>>(emb, embbf);
  k_wprep<<<(2 * 1024 * K_DIM) / 256, 256, 0, stream>>>(Wih_f, Whh_f, Wih_b, Whh_b, wptf, wptb);

  // grid 2048: b&1=dir, nblk=((b>>1)&3)*2+((b>>3)&1), rt=b>>4 (XCD-aware)
  for (int s = 0; s < T_LEN; ++s) {
    const ush* hrf = (s & 1) ? h1f : h0f;
    ush* hwf       = (s & 1) ? h0f : h1f;
    const ush* hrb = (s & 1) ? h1b : h0b;
    ush* hwb       = (s & 1) ? h0b : h1b;
    k_step<<<2048, 256, 0, stream>>>(embbf, tokperm, plens, cntsf, cntsb, wptf, wptb,
                                     b_f, b_b, hrf, hwf, hrb, hwb, cTf, cTb, s);
  }
  // final h in h0f / h0b (fwd graduation copies keep buffers synced; bwd ends at t=0 = s=15)
  k_pool<<<B_SAMP, 256, 0, stream>>>(h0f, h0b, pinv, plen, pooled);
  k_final<<<B_SAMP, 256, 0, stream>>>(pooled, Wlin, blin, out);
}